// Round 2
// baseline (132.026 us; speedup 1.0000x reference)
//
#include <hip/hip_runtime.h>
#include <math.h>

// CrossAttention B=2, Sq=Sk=2048, H=16, Hkv=4, D=64, fp32 io.
// R12: split-K. R10/R11 both pinned at ~67us dispatch with NO pipe >35%
// and occupancy 13-25% -> depth-bound on the 32-sequential-tile diagonal
// blocks (~2.1us per barrier-delimited tile iteration). Fixed-shift exp2
// softmax makes (o,l) pure linear sums over keys, so k-ranges split
// exactly. Each (b,h,qt) is chopped into chunks of <=8 k-tiles: 2560
// uniform main blocks (depth<=8). qt<=7 (1 chunk) writes out directly;
// qt>=8 writes fp32 (o,l) partials to d_ws (private slot per split, no
// atomics); a second stream-ordered kernel sums <=4 slots, normalizes,
// stores. Main tile loop is R5/R10-measured-optimal VERBATIM.

typedef __bf16 bf16x4 __attribute__((ext_vector_type(4)));
typedef __bf16 bf16x8 __attribute__((ext_vector_type(8)));
typedef float floatx4 __attribute__((ext_vector_type(4)));

#define B_ 2
#define SQ 2048
#define SK 2048
#define H_ 16
#define HKV 4
#define D_ 64
#define QT 64
#define KT 64
#define PADLD 72            // 144B rows (R5-measured layout)
#define KVROW 512           // floats per (b,s) slot: 2*HKV*D
#define NEGV (-10000.0f)
#define QSCL 0.18033688f    // 0.125 * log2(e)
#define EBIAS 17.3123405f   // fixed softmax shift (exp2 space)
#define SLOTF 4160          // floats per partial slot: 64*64 o + 64 l
#define SLOTS_PER_BH 72     // qt 8..15: 2 ea, 16..23: 3 ea, 24..31: 4 ea

__global__ __launch_bounds__(256, 4)
void attn_kernel(const float* __restrict__ q,
                 const float* __restrict__ kv,
                 const int* __restrict__ mask,
                 float* __restrict__ out,
                 float* __restrict__ ws)
{
    __shared__ alignas(16) __bf16 Kt[KT][PADLD];
    __shared__ alignas(16) __bf16 Vt[D_][PADLD];
    __shared__ alignas(16) __bf16 Pl[4][16][PADLD];
    __shared__ float fpart[4][64];          // fixup-only
    __shared__ float fw[4][64];             // fixup-only
    __shared__ int s_first;                 // fixup-only

    const int tid  = threadIdx.x;
    const int wave = tid >> 6;
    const int lane = tid & 63;
    const int col  = lane & 15;
    const int quad = lane >> 4;

    if (blockIdx.x < 32) {
        // ================= fixup role: rows R < first_kept[b] ===============
        const int bh = (int)blockIdx.x;
        const int b = bh >> 4, h = bh & 15, hkv = h >> 2;
        if (tid == 0) s_first = SK;
        __syncthreads();
        int local = SK;
        for (int s = tid; s < SK; s += 256)
            if (mask[b * SK + s]) local = min(local, s);
        atomicMin(&s_first, local);
        __syncthreads();
        const int nfirst = s_first;
        if (nfirst == 0) return;

        const float* kvb = kv + (size_t)b * SK * KVROW + hkv * D_;
        const float* vvb = kvb + HKV * D_;
        {
            float a0=0,a1=0,a2=0,a3=0,a4=0,a5=0,a6=0,a7=0;
            const int s0 = wave * 512;
            for (int s = s0; s < s0 + 512; s += 8) {
                a0 += vvb[(size_t)(s+0)*KVROW + lane];
                a1 += vvb[(size_t)(s+1)*KVROW + lane];
                a2 += vvb[(size_t)(s+2)*KVROW + lane];
                a3 += vvb[(size_t)(s+3)*KVROW + lane];
                a4 += vvb[(size_t)(s+4)*KVROW + lane];
                a5 += vvb[(size_t)(s+5)*KVROW + lane];
                a6 += vvb[(size_t)(s+6)*KVROW + lane];
                a7 += vvb[(size_t)(s+7)*KVROW + lane];
            }
            fpart[wave][lane] = ((a0+a1)+(a2+a3)) + ((a4+a5)+(a6+a7));
        }
        __syncthreads();
        const float vtotal = fpart[0][lane] + fpart[1][lane]
                           + fpart[2][lane] + fpart[3][lane];

        for (int R = wave; R < nfirst; R += 4) {
            const float* qrow = q + (((size_t)b * SQ + R) * H_ + h) * D_;
            float mymax = -3.4e38f;
            for (int s = lane; s <= R; s += 64) {
                const float* kp = kvb + (size_t)s * KVROW;
                float dt = 0.f;
                for (int d = 0; d < D_; ++d) dt += qrow[d] * kp[d];
                mymax = fmaxf(mymax, dt * 0.125f + NEGV);
            }
#pragma unroll
            for (int off = 32; off >= 1; off >>= 1)
                mymax = fmaxf(mymax, __shfl_xor(mymax, off, 64));
            const float M = (R < SK - 1) ? fmaxf(mymax, NEGV) : mymax;
            float lsum = 0.f, oacc = 0.f, pref = 0.f;
            for (int s0 = 0; s0 <= R; s0 += 64) {
                int s = s0 + lane;
                float w = 0.f;
                if (s <= R) {
                    const float* kp = kvb + (size_t)s * KVROW;
                    float dt = 0.f;
                    for (int d = 0; d < D_; ++d) dt += qrow[d] * kp[d];
                    w = __expf(dt * 0.125f + NEGV - M);
                    lsum += w;
                }
                fw[wave][lane] = w;   // wave-private, in-order
                const int nk = (R - s0 + 1 < 64) ? (R - s0 + 1) : 64;
                for (int j = 0; j < nk; ++j) {
                    const float vj = vvb[(size_t)(s0 + j) * KVROW + lane];
                    oacc += fw[wave][j] * vj;
                    pref += vj;
                }
            }
#pragma unroll
            for (int off = 32; off >= 1; off >>= 1)
                lsum += __shfl_xor(lsum, off, 64);
            const float wn   = __expf(NEGV - M);
            const float ltot = lsum + wn * (float)(SK - 1 - R);
            out[(((size_t)b * SQ + R) * H_ + h) * D_ + lane] =
                (oacc + wn * (vtotal - pref)) / ltot;
        }
        return;
    }

    // ================= main attention role (split-K chunks) ================
    const int id = (int)blockIdx.x - 32;
    const int bh = id & 31;
    const int z  = 79 - (id >> 5);        // deepest chunks dispatched first
    int qt, sp;
    if (z < 8)       { qt = z;                sp = 0; }
    else if (z < 24) { qt = 8 + ((z - 8) >> 1);  sp = (z - 8) & 1; }
    else if (z < 48) { qt = 16 + (z - 24) / 3;   sp = (z - 24) % 3; }
    else             { qt = 24 + ((z - 48) >> 2); sp = (z - 48) & 3; }
    const int nsplit = 1 + (qt >> 3);
    const int k0 = sp * 8;
    const int k1 = min(qt + 1, k0 + 8);

    const int b = bh >> 4, h = bh & 15, hkv = h >> 2;
    const int q0 = qt * QT;
    const int qw = q0 + wave * 16;

    // ---- Q A-fragments, pre-scaled into exp2 space ----
    bf16x8 aq[2];
    {
        const int row = qw + col;
        const float* qp = q + (((size_t)b * SQ + row) * H_ + h) * D_ + quad * 8;
#pragma unroll
        for (int kc = 0; kc < 2; ++kc) {
            const float* p = qp + kc * 32;
#pragma unroll
            for (int j = 0; j < 8; ++j) aq[kc][j] = (__bf16)(p[j] * QSCL);
        }
    }

    bf16x8 vone;
#pragma unroll
    for (int j = 0; j < 8; ++j) vone[j] = (__bf16)1.0f;

    floatx4 o[4];
    floatx4 l_acc = (floatx4){0.f, 0.f, 0.f, 0.f};
#pragma unroll
    for (int dj = 0; dj < 4; ++dj) o[dj] = (floatx4){0.f, 0.f, 0.f, 0.f};

    const int kkey = tid >> 4;
    const int kd   = (tid & 15) * 4;
    const int vkey = (tid & 15) * 4;
    const int vd   = (tid >> 4) * 4;

    const float* kvb = kv + (size_t)b * SK * KVROW + hkv * D_;

    float4 kreg[4], vreg[4];
    int mreg = 0;

    auto prefetch = [&](int kt) {
        const float* kb = kvb + (size_t)kt * KT * KVROW;
#pragma unroll
        for (int i = 0; i < 4; ++i)
            kreg[i] = *(const float4*)(kb + (kkey + 16 * i) * KVROW + kd);
        const float* vb = kb + HKV * D_;
#pragma unroll
        for (int i = 0; i < 4; ++i)
            vreg[i] = *(const float4*)(vb + (vkey + i) * KVROW + vd);
        mreg = mask[b * SK + kt * KT + lane];
    };

    auto stage = [&]() {
#pragma unroll
        for (int i = 0; i < 4; ++i) {
            bf16x4 t = { (__bf16)kreg[i].x, (__bf16)kreg[i].y,
                         (__bf16)kreg[i].z, (__bf16)kreg[i].w };
            *(bf16x4*)&Kt[kkey + 16 * i][kd] = t;
        }
        const float* vf = (const float*)vreg;
#pragma unroll
        for (int j = 0; j < 4; ++j) {
            bf16x4 t = { (__bf16)vf[0*4+j], (__bf16)vf[1*4+j],
                         (__bf16)vf[2*4+j], (__bf16)vf[3*4+j] };
            *(bf16x4*)&Vt[vd + j][vkey] = t;
        }
    };

    prefetch(k0);

    for (int kt = k0; kt < k1; ++kt) {
        stage();
        const unsigned long long kept = __ballot(mreg != 0);  // tile kt's mask
        __syncthreads();
        if (kt + 1 < k1) prefetch(kt + 1);   // lands during compute

        // ---- QK^T (exp2 space) ----
        floatx4 c[4];
#pragma unroll
        for (int kj = 0; kj < 4; ++kj) {
            c[kj] = (floatx4){0.f, 0.f, 0.f, 0.f};
#pragma unroll
            for (int kc = 0; kc < 2; ++kc) {
                bf16x8 bk = *(const bf16x8*)&Kt[kj * 16 + col][kc * 32 + quad * 8];
                c[kj] = __builtin_amdgcn_mfma_f32_16x16x32_bf16(aq[kc], bk, c[kj], 0, 0, 0);
            }
        }
        // ---- mask (ballot bit-test) + exp2 + P store (R5 pattern) ----
        const bool dg = (kt == qt);
        const int rowl = wave * 16 + quad * 4;
#pragma unroll
        for (int kj = 0; kj < 4; ++kj) {
            const int keyl = kj * 16 + col;
            const bool keep = (kept >> keyl) & 1ull;
#pragma unroll
            for (int r = 0; r < 4; ++r) {
                float p = __builtin_amdgcn_exp2f(c[kj][r] - EBIAS);
                if (!keep) p = 0.f;                       // pad: exact
                if (dg && keyl > rowl + r) p = 0.f;       // causal
                Pl[wave][quad * 4 + r][keyl] = (__bf16)p;
            }
        }
        // ---- P @ [V | ones] (wave-private LDS round-trip, no barrier) ----
        bf16x8 ap[2];
#pragma unroll
        for (int kc = 0; kc < 2; ++kc)
            ap[kc] = *(const bf16x8*)&Pl[wave][col][kc * 32 + quad * 8];
#pragma unroll
        for (int kc = 0; kc < 2; ++kc)
            l_acc = __builtin_amdgcn_mfma_f32_16x16x32_bf16(ap[kc], vone, l_acc, 0, 0, 0);
#pragma unroll
        for (int dj = 0; dj < 4; ++dj)
#pragma unroll
            for (int kc = 0; kc < 2; ++kc) {
                bf16x8 bv = *(const bf16x8*)&Vt[dj * 16 + col][kc * 32 + quad * 8];
                o[dj] = __builtin_amdgcn_mfma_f32_16x16x32_bf16(ap[kc], bv, o[dj], 0, 0, 0);
            }
        __syncthreads();
    }

    if (nsplit == 1) {
        // ---- direct epilogue: normalize + store (qt <= 7) ----
#pragma unroll
        for (int r = 0; r < 4; ++r) {
            const float l = l_acc[r];
            if (l > 0.f) {
                const float inv = 1.0f / l;
                const int row = qw + quad * 4 + r;
                float* op = out + (((size_t)b * SQ + row) * H_ + h) * D_ + col;
#pragma unroll
                for (int dj = 0; dj < 4; ++dj)
                    op[dj * 16] = o[dj][r] * inv;
            }
        }
    } else {
        // ---- partial epilogue: fp32 (o,l) to private ws slot (qt >= 8) ----
        const int local0 = (qt < 16) ? (qt - 8) * 2
                         : (qt < 24) ? 16 + (qt - 16) * 3
                                     : 40 + (qt - 24) * 4;
        float* slot = ws + ((size_t)bh * SLOTS_PER_BH + local0 + sp) * SLOTF;
#pragma unroll
        for (int r = 0; r < 4; ++r) {
            const int row = wave * 16 + quad * 4 + r;
            float* op = slot + (size_t)row * 64 + col;
#pragma unroll
            for (int dj = 0; dj < 4; ++dj)
                op[dj * 16] = o[dj][r];
            if (col == 0) slot[4096 + row] = l_acc[r];
        }
    }
}

__global__ __launch_bounds__(256)
void combine_kernel(const float* __restrict__ ws, float* __restrict__ out)
{
    __shared__ float linv[64];
    const int tid = threadIdx.x;
    const int bh = (int)blockIdx.x & 31;
    const int qt = 8 + ((int)blockIdx.x >> 5);
    const int b = bh >> 4, h = bh & 15;
    const int n = 1 + (qt >> 3);
    const int local0 = (qt < 16) ? (qt - 8) * 2
                     : (qt < 24) ? 16 + (qt - 16) * 3
                                 : 40 + (qt - 24) * 4;
    const float* s0 = ws + ((size_t)bh * SLOTS_PER_BH + local0) * SLOTF;

    if (tid < 64) {
        float s = 0.f;
        for (int k = 0; k < n; ++k)
            s += s0[(size_t)k * SLOTF + 4096 + tid];
        linv[tid] = (s > 0.f) ? 1.0f / s : 0.f;
    }
    __syncthreads();

#pragma unroll
    for (int c = 0; c < 4; ++c) {
        const int idx = c * 1024 + tid * 4;
        const int row = idx >> 6, d = idx & 63;
        float4 acc = *(const float4*)(s0 + idx);
        for (int k = 1; k < n; ++k) {
            const float4 t = *(const float4*)(s0 + (size_t)k * SLOTF + idx);
            acc.x += t.x; acc.y += t.y; acc.z += t.z; acc.w += t.w;
        }
        const float inv = linv[row];
        if (inv > 0.f) {
            float4 r4 = { acc.x * inv, acc.y * inv, acc.z * inv, acc.w * inv };
            *(float4*)(out + (((size_t)b * SQ + qt * 64 + row) * H_ + h) * D_ + d) = r4;
        }
    }
}

extern "C" void kernel_launch(void* const* d_in, const int* in_sizes, int n_in,
                              void* d_out, int out_size, void* d_ws, size_t ws_size,
                              hipStream_t stream) {
    const float* q   = (const float*)d_in[0];
    const float* kv  = (const float*)d_in[1];
    const int* mask  = (const int*)d_in[2];
    float* out       = (float*)d_out;
    attn_kernel<<<dim3(32 + 2560), 256, 0, stream>>>(q, kv, mask, out, (float*)d_ws);
    combine_kernel<<<dim3(768), 256, 0, stream>>>((const float*)d_ws, out);
}

// Round 3
// 123.009 us; speedup vs baseline: 1.0733x; 1.0733x over previous
//
#include <hip/hip_runtime.h>
#include <math.h>

// CrossAttention B=2, Sq=Sk=2048, H=16, Hkv=4, D=64, fp32 io.
// R13: kill the P LDS round-trip. R10/R11/R12 all pinned at 66us dispatch
// with no pipe >50% across 3 structures -> per-tile serial-chain bound.
// Swapped-operand QK^T: c = mfma(K_as_A, Q_as_B) (same LDS reads, same Q
// regs, operands swapped) puts S^T in registers with lane layout
// S[qrow=col][key16=quad*4+r] == the A-fragment layout of
// mfma_f32_16x16x16_bf16. PV = 16 x16-MFMAs with P straight from regs:
// no P stores, no lgkmcnt drain, no P reads, no Pl array (LDS 30->18.4KB),
// no P bank conflicts. l via 4 ones-MFMAs (x16). Single kernel, R10 snake
// schedule (split-K proved neutral; combine dispatch removed).

typedef __bf16 bf16x4 __attribute__((ext_vector_type(4)));
typedef __bf16 bf16x8 __attribute__((ext_vector_type(8)));
typedef float floatx4 __attribute__((ext_vector_type(4)));
typedef short shortx4 __attribute__((ext_vector_type(4)));

#define B_ 2
#define SQ 2048
#define SK 2048
#define H_ 16
#define HKV 4
#define D_ 64
#define QT 64
#define KT 64
#define PADLD 72            // 144B rows (R5-measured layout)
#define KVROW 512           // floats per (b,s) slot: 2*HKV*D
#define NEGV (-10000.0f)
#define QSCL 0.18033688f    // 0.125 * log2(e)
#define EBIAS 17.3123405f   // fixed softmax shift (exp2 space)

static __device__ __forceinline__ floatx4 mfma16(bf16x4 a, bf16x4 b, floatx4 c) {
#if __has_builtin(__builtin_amdgcn_mfma_f32_16x16x16bf16_1k)
    return __builtin_amdgcn_mfma_f32_16x16x16bf16_1k(
        __builtin_bit_cast(shortx4, a), __builtin_bit_cast(shortx4, b), c, 0, 0, 0);
#else
    floatx4 d;
    asm("v_mfma_f32_16x16x16_bf16 %0, %1, %2, %3"
        : "=v"(d) : "v"(a), "v"(b), "v"(c));
    return d;
#endif
}

__global__ __launch_bounds__(256, 4)
void attn_kernel(const float* __restrict__ q,
                 const float* __restrict__ kv,
                 const int* __restrict__ mask,
                 float* __restrict__ out)
{
    __shared__ alignas(16) union {
        struct {
            __bf16 Kt[KT][PADLD];
            __bf16 Vt[D_][PADLD];
        } m;
        struct {                    // fixup role only (blocks 0..31)
            float fpart[4][64];
            float fw[4][64];
            int   s_first;
        } f;
    } sh;

    const int tid  = threadIdx.x;
    const int wave = tid >> 6;
    const int lane = tid & 63;
    const int col  = lane & 15;
    const int quad = lane >> 4;

    if (blockIdx.x < 32) {
        // ================= fixup role: rows R < first_kept[b] ===============
        const int bh = (int)blockIdx.x;
        const int b = bh >> 4, h = bh & 15, hkv = h >> 2;
        if (tid == 0) sh.f.s_first = SK;
        __syncthreads();
        int local = SK;
        for (int s = tid; s < SK; s += 256)
            if (mask[b * SK + s]) local = min(local, s);
        atomicMin(&sh.f.s_first, local);
        __syncthreads();
        const int nfirst = sh.f.s_first;
        if (nfirst == 0) return;

        const float* kvb = kv + (size_t)b * SK * KVROW + hkv * D_;
        const float* vvb = kvb + HKV * D_;
        {
            float a0=0,a1=0,a2=0,a3=0,a4=0,a5=0,a6=0,a7=0;
            const int s0 = wave * 512;
            for (int s = s0; s < s0 + 512; s += 8) {
                a0 += vvb[(size_t)(s+0)*KVROW + lane];
                a1 += vvb[(size_t)(s+1)*KVROW + lane];
                a2 += vvb[(size_t)(s+2)*KVROW + lane];
                a3 += vvb[(size_t)(s+3)*KVROW + lane];
                a4 += vvb[(size_t)(s+4)*KVROW + lane];
                a5 += vvb[(size_t)(s+5)*KVROW + lane];
                a6 += vvb[(size_t)(s+6)*KVROW + lane];
                a7 += vvb[(size_t)(s+7)*KVROW + lane];
            }
            sh.f.fpart[wave][lane] = ((a0+a1)+(a2+a3)) + ((a4+a5)+(a6+a7));
        }
        __syncthreads();
        const float vtotal = sh.f.fpart[0][lane] + sh.f.fpart[1][lane]
                           + sh.f.fpart[2][lane] + sh.f.fpart[3][lane];

        for (int R = wave; R < nfirst; R += 4) {
            const float* qrow = q + (((size_t)b * SQ + R) * H_ + h) * D_;
            float mymax = -3.4e38f;
            for (int s = lane; s <= R; s += 64) {
                const float* kp = kvb + (size_t)s * KVROW;
                float dt = 0.f;
                for (int d = 0; d < D_; ++d) dt += qrow[d] * kp[d];
                mymax = fmaxf(mymax, dt * 0.125f + NEGV);
            }
#pragma unroll
            for (int off = 32; off >= 1; off >>= 1)
                mymax = fmaxf(mymax, __shfl_xor(mymax, off, 64));
            const float M = (R < SK - 1) ? fmaxf(mymax, NEGV) : mymax;
            float lsum = 0.f, oacc = 0.f, pref = 0.f;
            for (int s0 = 0; s0 <= R; s0 += 64) {
                int s = s0 + lane;
                float w = 0.f;
                if (s <= R) {
                    const float* kp = kvb + (size_t)s * KVROW;
                    float dt = 0.f;
                    for (int d = 0; d < D_; ++d) dt += qrow[d] * kp[d];
                    w = __expf(dt * 0.125f + NEGV - M);
                    lsum += w;
                }
                sh.f.fw[wave][lane] = w;   // wave-private, in-order
                const int nk = (R - s0 + 1 < 64) ? (R - s0 + 1) : 64;
                for (int j = 0; j < nk; ++j) {
                    const float vj = vvb[(size_t)(s0 + j) * KVROW + lane];
                    oacc += sh.f.fw[wave][j] * vj;
                    pref += vj;
                }
            }
#pragma unroll
            for (int off = 32; off >= 1; off >>= 1)
                lsum += __shfl_xor(lsum, off, 64);
            const float wn   = __expf(NEGV - M);
            const float ltot = lsum + wn * (float)(SK - 1 - R);
            out[(((size_t)b * SQ + R) * H_ + h) * D_ + lane] =
                (oacc + wn * (vtotal - pref)) / ltot;
        }
        return;
    }

    // ================= main attention role ================================
    const int id = (int)blockIdx.x - 32;
    const int bh = id & 31;
    const int y  = id >> 5;               // 0..31
    const int kg = y >> 3, jj = y & 7;    // quad {31-j, j, 23-j, 8+j}: 66 tiles
    const int qt = (kg == 0) ? 31 - jj : (kg == 1) ? jj : (kg == 2) ? 23 - jj : 8 + jj;
    const int b = bh >> 4, h = bh & 15, hkv = h >> 2;
    const int q0 = qt * QT;
    const int qw = q0 + wave * 16;

    // ---- Q B-fragments (swapped QK), pre-scaled into exp2 space ----
    // B[k=d][n=qrow16]: lane needs Q[qw+col][kc*32+quad*8+j] — identical
    // load pattern to the old A-fragment.
    bf16x8 aq[2];
    {
        const int row = qw + col;
        const float* qp = q + (((size_t)b * SQ + row) * H_ + h) * D_ + quad * 8;
#pragma unroll
        for (int kc = 0; kc < 2; ++kc) {
            const float* p = qp + kc * 32;
#pragma unroll
            for (int j = 0; j < 8; ++j) aq[kc][j] = (__bf16)(p[j] * QSCL);
        }
    }

    bf16x4 vone4;
#pragma unroll
    for (int j = 0; j < 4; ++j) vone4[j] = (__bf16)1.0f;

    floatx4 o[4];
    floatx4 l_acc = (floatx4){0.f, 0.f, 0.f, 0.f};
#pragma unroll
    for (int dj = 0; dj < 4; ++dj) o[dj] = (floatx4){0.f, 0.f, 0.f, 0.f};

    const int kkey = tid >> 4;
    const int kd   = (tid & 15) * 4;
    const int vkey = (tid & 15) * 4;
    const int vd   = (tid >> 4) * 4;

    const float* kvb = kv + (size_t)b * SK * KVROW + hkv * D_;

    float4 kreg[4], vreg[4];
    int mreg = 0;

    auto prefetch = [&](int kt) {
        const float* kb = kvb + (size_t)kt * KT * KVROW;
#pragma unroll
        for (int i = 0; i < 4; ++i)
            kreg[i] = *(const float4*)(kb + (kkey + 16 * i) * KVROW + kd);
        const float* vb = kb + HKV * D_;
#pragma unroll
        for (int i = 0; i < 4; ++i)
            vreg[i] = *(const float4*)(vb + (vkey + i) * KVROW + vd);
        mreg = mask[b * SK + kt * KT + lane];
    };

    auto stage = [&]() {
#pragma unroll
        for (int i = 0; i < 4; ++i) {
            bf16x4 t = { (__bf16)kreg[i].x, (__bf16)kreg[i].y,
                         (__bf16)kreg[i].z, (__bf16)kreg[i].w };
            *(bf16x4*)&sh.m.Kt[kkey + 16 * i][kd] = t;
        }
        const float* vf = (const float*)vreg;
#pragma unroll
        for (int j = 0; j < 4; ++j) {
            bf16x4 t = { (__bf16)vf[0*4+j], (__bf16)vf[1*4+j],
                         (__bf16)vf[2*4+j], (__bf16)vf[3*4+j] };
            *(bf16x4*)&sh.m.Vt[vd + j][vkey] = t;
        }
    };

    const int nkt = qt + 1;
    prefetch(0);

    for (int kt = 0; kt < nkt; ++kt) {
        stage();
        const unsigned long long kept = __ballot(mreg != 0);  // tile kt's mask
        __syncthreads();
        if (kt + 1 < nkt) prefetch(kt + 1);   // lands during compute

        // ---- QK^T swapped: c[kj] = S^T block, lane holds
        //      S[qrow=col][key16=quad*4+r] ----
        floatx4 c[4];
#pragma unroll
        for (int kj = 0; kj < 4; ++kj) {
            c[kj] = (floatx4){0.f, 0.f, 0.f, 0.f};
#pragma unroll
            for (int kc = 0; kc < 2; ++kc) {
                bf16x8 ak = *(const bf16x8*)&sh.m.Kt[kj * 16 + col][kc * 32 + quad * 8];
                c[kj] = __builtin_amdgcn_mfma_f32_16x16x32_bf16(ak, aq[kc], c[kj], 0, 0, 0);
            }
        }

        // ---- mask + exp2, fully lane-local; P packed in regs ----
        const bool dg = (kt == qt);
        const unsigned long long kq = kept >> (quad * 4);   // bit (kj*16+r)
        const int tcl = dg ? (wave * 16 + col - quad * 4) : 127;  // keys kj*16+r > tcl masked
        bf16x4 pk[4];
#pragma unroll
        for (int kj = 0; kj < 4; ++kj) {
#pragma unroll
            for (int r = 0; r < 4; ++r) {
                float p = __builtin_amdgcn_exp2f(c[kj][r] - EBIAS);
                const bool keep = ((kq >> (kj * 16 + r)) & 1ull) && (kj * 16 + r <= tcl);
                pk[kj][r] = (__bf16)(keep ? p : 0.f);
            }
        }

        // ---- l via ones-MFMA (x16), P straight from regs ----
#pragma unroll
        for (int kj = 0; kj < 4; ++kj)
            l_acc = mfma16(pk[kj], vone4, l_acc);

        // ---- PV: 16 x16-MFMAs, V B-frags as ds_read_b64 ----
#pragma unroll
        for (int dj = 0; dj < 4; ++dj)
#pragma unroll
            for (int kj = 0; kj < 4; ++kj) {
                bf16x4 bv = *(const bf16x4*)&sh.m.Vt[dj * 16 + col][kj * 16 + quad * 4];
                o[dj] = mfma16(pk[kj], bv, o[dj]);
            }
        __syncthreads();
    }

    // ---- epilogue: normalize + store; l==0 rows written by fixup role ----
#pragma unroll
    for (int r = 0; r < 4; ++r) {
        const float l = l_acc[r];
        if (l > 0.f) {
            const float inv = 1.0f / l;
            const int row = qw + quad * 4 + r;
            float* op = out + (((size_t)b * SQ + row) * H_ + h) * D_ + col;
#pragma unroll
            for (int dj = 0; dj < 4; ++dj)
                op[dj * 16] = o[dj][r] * inv;
        }
    }
}

extern "C" void kernel_launch(void* const* d_in, const int* in_sizes, int n_in,
                              void* d_out, int out_size, void* d_ws, size_t ws_size,
                              hipStream_t stream) {
    const float* q   = (const float*)d_in[0];
    const float* kv  = (const float*)d_in[1];
    const int* mask  = (const int*)d_in[2];
    float* out       = (float*)d_out;
    attn_kernel<<<dim3(32 + 1024), 256, 0, stream>>>(q, kv, mask, out);
}